// Round 1
// baseline (321.136 us; speedup 1.0000x reference)
//
#include <hip/hip_runtime.h>

#define NB    128   // batch
#define NC    12    // channels
#define NL    1024  // length
#define NDIL  7
#define NDIV  2
#define NH    32
#define NK    8
#define NKSZ  9
#define NNCP  6
#define PAD   256           // max (KSZ-1)/2 * d = 4*64
#define LG    (NL + 2*PAD)  // 1536
#define OUTPB (NDIL*NDIV*2*NH*NK)  // 7168 per batch element

__global__ __launch_bounds__(256) void hydra_kernel(
    const float* __restrict__ X,   // [B, C, L]
    const float* __restrict__ W,   // [NDIL, NDIV, K*H, 1, KSZ]
    const int*   __restrict__ I,   // [NDIL, NDIV, H, NCP]
    float*       __restrict__ out) // [B, 28*H*K]
{
    __shared__ float g[LG];
    __shared__ float red[4 * 16];

    const int bid = blockIdx.x;
    const int h   = bid & 31;
    const int tmp = bid >> 5;          // b*14 + dj
    const int dj  = tmp % 14;
    const int b   = tmp / 14;
    const int di  = dj >> 1;
    const int j   = dj & 1;
    const int d   = 1 << di;
    const int Lp  = (j == 0) ? NL : (NL - 1);

    const int tid = threadIdx.x;

    // --- gather-sum into padded LDS series -------------------------------
    int ic[NNCP];
    {
        const int* idx = I + ((di * NDIV + j) * NH + h) * NNCP;
        #pragma unroll
        for (int c = 0; c < NNCP; ++c) ic[c] = idx[c];
    }
    const float* Xb = X + (size_t)b * NC * NL;

    g[tid]            = 0.f;   // front pad [0,256)
    g[LG - 256 + tid] = 0.f;   // back pad [1280,1536)

    for (int l = tid; l < NL; l += 256) {
        float s = 0.f;
        if (l < Lp) {
            if (j == 0) {
                #pragma unroll
                for (int c = 0; c < NNCP; ++c) s += Xb[ic[c] * NL + l];
            } else {
                #pragma unroll
                for (int c = 0; c < NNCP; ++c)
                    s += Xb[ic[c] * NL + l + 1] - Xb[ic[c] * NL + l];
            }
        }
        g[PAD + l] = s;        // also zeroes index PAD+1023 when j==1
    }
    __syncthreads();

    // --- weights into registers (uniform across lanes) -------------------
    float w[NKSZ][NK];
    {
        const float* Wp = W + (size_t)((di * NDIV + j) * (NK * NH) + h * NK) * NKSZ;
        #pragma unroll
        for (int k = 0; k < NK; ++k)
            #pragma unroll
            for (int t = 0; t < NKSZ; ++t) w[t][k] = Wp[k * NKSZ + t];
    }

    // --- dilated correlation: 4 positions/thread, 8 filters --------------
    float acc[4][NK];
    #pragma unroll
    for (int pp = 0; pp < 4; ++pp)
        #pragma unroll
        for (int k = 0; k < NK; ++k) acc[pp][k] = 0.f;

    #pragma unroll
    for (int t = 0; t < NKSZ; ++t) {
        const int off = PAD + (t - 4) * d + tid;
        const float gv0 = g[off];
        const float gv1 = g[off + 256];
        const float gv2 = g[off + 512];
        const float gv3 = g[off + 768];
        #pragma unroll
        for (int k = 0; k < NK; ++k) {
            const float wk = w[t][k];
            acc[0][k] = fmaf(wk, gv0, acc[0][k]);
            acc[1][k] = fmaf(wk, gv1, acc[1][k]);
            acc[2][k] = fmaf(wk, gv2, acc[2][k]);
            acc[3][k] = fmaf(wk, gv3, acc[3][k]);
        }
    }

    // --- per-position argmax/argmin -> per-thread bins (static indexing) -
    float cm[NK], cn[NK];
    #pragma unroll
    for (int k = 0; k < NK; ++k) { cm[k] = 0.f; cn[k] = 0.f; }

    #pragma unroll
    for (int pp = 0; pp < 4; ++pp) {
        const int l = tid + pp * 256;
        if (l < Lp) {
            float mx = acc[pp][0], mn = acc[pp][0];
            int ax = 0, an = 0;
            #pragma unroll
            for (int k = 1; k < NK; ++k) {
                if (acc[pp][k] > mx) { mx = acc[pp][k]; ax = k; }
                if (acc[pp][k] < mn) { mn = acc[pp][k]; an = k; }
            }
            #pragma unroll
            for (int k = 0; k < NK; ++k) {
                cm[k] += (k == ax) ? mx : 0.f;
                cn[k] += (k == an) ? 1.f : 0.f;
            }
        }
    }

    // --- block reduction: wave shuffle tree, then cross-wave via LDS -----
    #pragma unroll
    for (int k = 0; k < NK; ++k) {
        #pragma unroll
        for (int s = 32; s > 0; s >>= 1) {
            cm[k] += __shfl_down(cm[k], s, 64);
            cn[k] += __shfl_down(cn[k], s, 64);
        }
    }
    const int lane = tid & 63, wid = tid >> 6;
    if (lane == 0) {
        #pragma unroll
        for (int k = 0; k < NK; ++k) {
            red[wid * 16 + k]      = cm[k];
            red[wid * 16 + 8 + k]  = cn[k];
        }
    }
    __syncthreads();

    if (tid < 16) {
        const float s = red[tid] + red[16 + tid] + red[32 + tid] + red[48 + tid];
        const int z = (di * NDIV + j) * 2 + (tid >> 3);   // max then min
        out[(size_t)b * OUTPB + z * (NH * NK) + h * NK + (tid & 7)] = s;
    }
}

extern "C" void kernel_launch(void* const* d_in, const int* in_sizes, int n_in,
                              void* d_out, int out_size, void* d_ws, size_t ws_size,
                              hipStream_t stream) {
    const float* X = (const float*)d_in[0];
    const float* W = (const float*)d_in[1];
    const int*   I = (const int*)d_in[2];
    float* out = (float*)d_out;

    const int nblocks = NB * NDIL * NDIV * NH;   // 57344
    hydra_kernel<<<dim3(nblocks), dim3(256), 0, stream>>>(X, W, I, out);
}

// Round 2
// 221.449 us; speedup vs baseline: 1.4502x; 1.4502x over previous
//
#include <hip/hip_runtime.h>

#define NB 128
#define NC 12
#define NL 1024
#define NDIL 7
#define NDIV 2
#define NH 32
#define NK 8
#define NKSZ 9
#define NNCP 6
#define PAD 256
#define LG (NL + 2*PAD)            // 1536
#define OUTPB (NDIL*NDIV*2*NH*NK)  // 7168

__global__ __launch_bounds__(256) void hydra_kernel(
    const float* __restrict__ X,   // [B, C, L]
    const float* __restrict__ W,   // [NDIL, NDIV, K*H, 1, KSZ]
    const int*   __restrict__ I,   // [NDIL, NDIV, H, NCP]
    float*       __restrict__ out) // [B, 28*H*K]
{
    __shared__ float g[4][LG];     // one padded series per wave (per h)
    __shared__ float red[4][16];

    const int bid = blockIdx.x;
    const int h4 = bid & 7;
    const int dj = (bid >> 3) % 14;
    const int b  = (bid >> 3) / 14;
    const int di = dj >> 1;
    const int j  = dj & 1;
    const int d  = 1 << di;

    const int tid  = threadIdx.x;
    const int lane = tid & 63;
    const int wid  = __builtin_amdgcn_readfirstlane(tid >> 6);
    const int h    = h4 * 4 + wid;          // wave-uniform

    float* gw = g[wid];

    // zero pads: [0,256) and [1280,1536)
    #pragma unroll
    for (int r = 0; r < 4; ++r) {
        gw[lane + 64*r]            = 0.f;
        gw[PAD + NL + lane + 64*r] = 0.f;
    }

    // wave-uniform channel pointers -> scalar loads
    const int* idx = I + ((di*NDIV + j)*NH + h)*NNCP;
    const float* xb = X + (size_t)b * NC * NL;
    const float* p0 = xb + idx[0]*NL;
    const float* p1 = xb + idx[1]*NL;
    const float* p2 = xb + idx[2]*NL;
    const float* p3 = xb + idx[3]*NL;
    const float* p4 = xb + idx[4]*NL;
    const float* p5 = xb + idx[5]*NL;

    if (j == 0) {
        #pragma unroll 4
        for (int c = 0; c < 16; ++c) {
            const int l = lane + 64*c;
            gw[PAD + l] = p0[l]+p1[l]+p2[l]+p3[l]+p4[l]+p5[l];
        }
    } else {
        #pragma unroll 2
        for (int c = 0; c < 16; ++c) {
            const int l = lane + 64*c;
            float s = 0.f;
            if (l < NL-1) {   // diff series has length L-1; last slot stays 0
                s = (p0[l+1]-p0[l]) + (p1[l+1]-p1[l]) + (p2[l+1]-p2[l])
                  + (p3[l+1]-p3[l]) + (p4[l+1]-p4[l]) + (p5[l+1]-p5[l]);
            }
            gw[PAD + l] = s;
        }
    }
    __syncthreads();

    // wave-uniform weights -> SGPRs
    const float* Wp = W + (size_t)((di*NDIV + j)*(NK*NH) + h*NK) * NKSZ;
    float w[NK][NKSZ];
    #pragma unroll
    for (int k = 0; k < NK; ++k)
        #pragma unroll
        for (int t = 0; t < NKSZ; ++t)
            w[k][t] = Wp[k*NKSZ + t];

    float cm[NK];
    int   cn[NK];
    #pragma unroll
    for (int k = 0; k < NK; ++k) { cm[k] = 0.f; cn[k] = 0; }

    const int lastp = NL - 1 - j;   // last valid output position

#define ARGBIN(A, LPOS)                                                   \
    {                                                                     \
        float mx = fmaxf(A[0], A[1]);                                     \
        mx = fmaxf(mx, A[2]); mx = fmaxf(mx, A[3]);                       \
        mx = fmaxf(mx, A[4]); mx = fmaxf(mx, A[5]);                       \
        mx = fmaxf(mx, A[6]); mx = fmaxf(mx, A[7]);                       \
        float mn = fminf(A[0], A[1]);                                     \
        mn = fminf(mn, A[2]); mn = fminf(mn, A[3]);                       \
        mn = fminf(mn, A[4]); mn = fminf(mn, A[5]);                       \
        mn = fminf(mn, A[6]); mn = fminf(mn, A[7]);                       \
        if ((LPOS) <= lastp) {                                            \
            _Pragma("unroll")                                             \
            for (int k = 0; k < NK; ++k) {                                \
                cm[k] += (A[k] == mx) ? A[k] : 0.f;                       \
                cn[k] += (A[k] == mn) ? 1 : 0;                            \
            }                                                             \
        }                                                                 \
    }

    if (d == 1) {
        // dilation 1: sliding 10-value window, 5 aligned b64 reads per pair
        for (int c = 0; c < 8; ++c) {
            const int pbase = 128*c + 2*lane;
            const float* base = gw + (PAD - 4) + pbase;   // even dword -> 8B aligned
            float win[10];
            #pragma unroll
            for (int r = 0; r < 5; ++r) {
                const float2 v = *(const float2*)(base + 2*r);
                win[2*r] = v.x; win[2*r+1] = v.y;
            }
            float a0[NK], a1[NK];
            #pragma unroll
            for (int k = 0; k < NK; ++k) { a0[k] = 0.f; a1[k] = 0.f; }
            #pragma unroll
            for (int t = 0; t < NKSZ; ++t)
                #pragma unroll
                for (int k = 0; k < NK; ++k) {
                    a0[k] = fmaf(w[k][t], win[t],   a0[k]);
                    a1[k] = fmaf(w[k][t], win[t+1], a1[k]);
                }
            ARGBIN(a0, pbase);
            ARGBIN(a1, pbase + 1);
        }
    } else {
        // dilation >=2: tap offsets even -> one aligned b64 read serves both positions
        for (int c = 0; c < 8; ++c) {
            const int pbase = 128*c + 2*lane;
            const float* base = gw + PAD + pbase;         // even dword -> 8B aligned
            float a0[NK], a1[NK];
            #pragma unroll
            for (int k = 0; k < NK; ++k) { a0[k] = 0.f; a1[k] = 0.f; }
            #pragma unroll
            for (int t = 0; t < NKSZ; ++t) {
                const float2 v = *(const float2*)(base + (t-4)*d);
                #pragma unroll
                for (int k = 0; k < NK; ++k) {
                    a0[k] = fmaf(w[k][t], v.x, a0[k]);
                    a1[k] = fmaf(w[k][t], v.y, a1[k]);
                }
            }
            ARGBIN(a0, pbase);
            ARGBIN(a1, pbase + 1);
        }
    }
#undef ARGBIN

    // wave reduction: 16 bins, amortized over 1024 positions
    #pragma unroll
    for (int k = 0; k < NK; ++k) {
        #pragma unroll
        for (int s = 32; s > 0; s >>= 1) {
            cm[k] += __shfl_down(cm[k], s, 64);
            cn[k] += __shfl_down(cn[k], s, 64);
        }
    }
    if (lane == 0) {
        #pragma unroll
        for (int k = 0; k < NK; ++k) {
            red[wid][k]     = cm[k];
            red[wid][8 + k] = (float)cn[k];
        }
    }
    __syncthreads();

    if (tid < 64) {
        const int ws = tid >> 4, slot = tid & 15;
        const int mm = slot >> 3, k = slot & 7;
        const int ho = h4*4 + ws;
        const int z  = dj*2 + mm;                 // [max, min] per (di,j)
        out[(size_t)b*OUTPB + z*(NH*NK) + ho*NK + k] = red[ws][slot];
    }
}

extern "C" void kernel_launch(void* const* d_in, const int* in_sizes, int n_in,
                              void* d_out, int out_size, void* d_ws, size_t ws_size,
                              hipStream_t stream) {
    const float* X = (const float*)d_in[0];
    const float* W = (const float*)d_in[1];
    const int*   I = (const int*)d_in[2];
    float* out = (float*)d_out;

    const int nblocks = NB * (NDIL*NDIV) * (NH/4);   // 128*14*8 = 14336
    hydra_kernel<<<dim3(nblocks), dim3(256), 0, stream>>>(X, W, I, out);
}